// Round 18
// baseline (321.358 us; speedup 1.0000x reference)
//
#include <hip/hip_runtime.h>
#include <hip/hip_bf16.h>
#include <math.h>

#define S_LEN 2048
#define DIMM 2048
#define NH 16
#define HD 128
#define QKV_ELEMS (2 * NH * S_LEN * HD)   // 8388608 = 4096*2048

typedef __attribute__((ext_vector_type(8))) short short8;
typedef __attribute__((ext_vector_type(4))) float f32x4;
typedef __attribute__((ext_vector_type(16))) float f32x16;

static __device__ __forceinline__ ushort f2bf(float x) {
  union { float f; unsigned u; } v; v.f = x;
  unsigned r = v.u + 0x7fffu + ((v.u >> 16) & 1u);   // RNE
  return (ushort)(r >> 16);
}
static __device__ __forceinline__ float bf2f(ushort u) {
  union { unsigned u; float f; } v; v.u = ((unsigned)u) << 16;
  return v.f;
}
static __device__ __forceinline__ unsigned pk2(float a, float b) {
  return (unsigned)f2bf(a) | ((unsigned)f2bf(b) << 16);  // low = a, high = b
}
static __device__ __forceinline__ f32x4 MF(uint4 a, uint4 b, f32x4 c) {
  return __builtin_amdgcn_mfma_f32_16x16x32_bf16(
      __builtin_bit_cast(short8, a), __builtin_bit_cast(short8, b), c, 0, 0, 0);
}

#define GLD16(gp, lp)                                                        \
  __builtin_amdgcn_global_load_lds(                                          \
      (const __attribute__((address_space(1))) void*)(gp),                   \
      (__attribute__((address_space(3))) void*)(lp), 16, 0, 0)

// ------- fused prep: bf16 casts (h,wq,wk,wv) + wo->bf16 + RoPE table ---------------
__global__ __launch_bounds__(256) void prep_kernel(
    const float* __restrict__ h, const float* __restrict__ wq,
    const float* __restrict__ wk, const float* __restrict__ wv,
    const float* __restrict__ wo,
    ushort* __restrict__ hb, ushort* __restrict__ wqb,
    ushort* __restrict__ wkb, ushort* __restrict__ wvb,
    ushort* __restrict__ woh,
    float* __restrict__ cost, float* __restrict__ sint) {
  const int C_ALL = 5 << 20;      // float4 units: h 2M, wq/wk/wv 1M each
  const int C_WO  = 1 << 20;      // wo float4 units
  const int C_TAB = 32768;        // table: 2048 pos x 16 j-quads
  const int total = C_ALL + C_WO + C_TAB;
  for (int idx = blockIdx.x * 256 + threadIdx.x; idx < total; idx += gridDim.x * 256) {
    if (idx < C_ALL + C_WO) {
      int u = idx >> 20;
      const float* src; ushort* dst; int off;
      if (u < 2)      { src = h;  dst = hb;  off = idx; }
      else if (u == 2){ src = wq; dst = wqb; off = idx - (2 << 20); }
      else if (u == 3){ src = wk; dst = wkb; off = idx - (3 << 20); }
      else if (u == 4){ src = wv; dst = wvb; off = idx - (4 << 20); }
      else            { src = wo; dst = woh; off = idx - (5 << 20); }
      float4 x = ((const float4*)src)[off];
      ushort4 y;
      y.x = f2bf(x.x); y.y = f2bf(x.y); y.z = f2bf(x.z); y.w = f2bf(x.w);
      ((ushort4*)dst)[off] = y;
    } else {
      int r = idx - C_ALL - C_WO;
      int p = r >> 4;
      int j0 = (r & 15) * 4;
#pragma unroll
      for (int e = 0; e < 4; ++e) {
        int j = j0 + e;
        double invf = pow(10000.0, -((double)(2 * j) / 128.0));
        double a = (double)p * invf;
        cost[(p << 6) + j] = (float)cos(a);
        sint[(p << 6) + j] = (float)sin(a);
      }
    }
  }
}

// ---------------- m97-style bf16 NT GEMM core: 128x128 tile, BK=64 -----------------
__device__ __forceinline__ void gemm_tile_loop(
    const ushort* __restrict__ A, const ushort* __restrict__ B,
    int brow, int bcol, ushort* ldsA, ushort* ldsB,
    int wid, int lane, f32x4 (&acc)[4][4]) {
  const int g = lane >> 4, lr = lane & 15;
  const int wr = wid >> 1, wc = wid & 1;
  const int srow = lane >> 3;   // 0..7
  const int slot = lane & 7;    // 16B slot (8 bf16)
  const ushort* Abase = A + ((size_t)(brow * 128 + wid * 32 + srow)) * DIMM + slot * 8;
  const ushort* Bbase = B + ((size_t)(bcol * 128 + wid * 32 + srow)) * DIMM + slot * 8;
  for (int k0 = 0; k0 < DIMM; k0 += 64) {
#pragma unroll
    for (int i = 0; i < 4; ++i) {
      GLD16(Abase + (size_t)i * 8 * DIMM + k0, ldsA + (wid * 4 + i) * 512);
      GLD16(Bbase + (size_t)i * 8 * DIMM + k0, ldsB + (wid * 4 + i) * 512);
    }
    __syncthreads();
    uint4 av[4][2], bv[4][2];
#pragma unroll
    for (int m = 0; m < 4; ++m)
#pragma unroll
      for (int ks = 0; ks < 2; ++ks) {
        av[m][ks] = *(const uint4*)(ldsA + (wr * 64 + m * 16 + lr) * 64 + ks * 32 + g * 8);
        bv[m][ks] = *(const uint4*)(ldsB + (wc * 64 + m * 16 + lr) * 64 + ks * 32 + g * 8);
      }
#pragma unroll
    for (int ks = 0; ks < 2; ++ks)
#pragma unroll
      for (int m = 0; m < 4; ++m)
#pragma unroll
        for (int n = 0; n < 4; ++n)
          acc[m][n] = MF(av[m][ks], bv[n][ks], acc[m][n]);
    __syncthreads();
  }
}

// ---------------- fused QKV projection GEMM: W = [wq;wk;wv] 6144 rows --------------
// Q,K written [bh][s][d]; V written TRANSPOSED [bh][d][s] (ushort4 stores) so the
// attention kernel can stage V^T linearly via global_load_lds (no LDS scatter).
__global__ __launch_bounds__(256) void gemm_qkv_kernel(
    const ushort* __restrict__ A, const ushort* __restrict__ W,
    ushort* __restrict__ qk_dst, ushort* __restrict__ vT) {
  __shared__ ushort ldsA[128 * 64];
  __shared__ ushort ldsB[128 * 64];
  const int t = threadIdx.x;
  const int lane = t & 63, wid = t >> 6;
  int bid = blockIdx.x;                       // 1536 blocks (32 brows x 48 bcols)
  int xcd = bid & 7;
  int idx = bid >> 3;                         // 0..191
  int chunk = idx >> 4;                       // 0..11
  int sub = idx & 15;
  const int brow = xcd * 4 + (sub >> 2);
  const int bcol = chunk * 4 + (sub & 3);
  f32x4 acc[4][4];
#pragma unroll
  for (int m = 0; m < 4; ++m)
#pragma unroll
    for (int n = 0; n < 4; ++n) acc[m][n] = (f32x4){0.f, 0.f, 0.f, 0.f};
  gemm_tile_loop(A, W, brow, bcol, ldsA, ldsB, wid, lane, acc);
  const int g = lane >> 4, lr = lane & 15;
  const int wr = wid >> 1, wc = wid & 1;
  const int tensor = bcol >> 4;               // uniform per block
  if (tensor < 2) {
    // Q or K: [bh][s][d] scattered u16 stores (round-14 verified)
#pragma unroll
    for (int n = 0; n < 4; ++n) {
      int jcol = bcol * 128 + wc * 64 + n * 16 + lr;
      int c2 = jcol & 2047;
      int hh = c2 >> 7, dd = c2 & 127;
      ushort* dst = qk_dst + (size_t)tensor * QKV_ELEMS;
#pragma unroll
      for (int m = 0; m < 4; ++m) {
        int i0 = brow * 128 + wr * 64 + m * 16 + g * 4;
#pragma unroll
        for (int r = 0; r < 4; ++r) {
          int tok = i0 + r;
          int bb = tok >> 11, ss = tok & 2047;
          dst[(((size_t)(bb * NH + hh)) * S_LEN + ss) * HD + dd] = f2bf(acc[m][n][r]);
        }
      }
    }
  } else {
    // V: transposed [bh][d][s]; r walks 4 consecutive tokens -> ushort4 store
#pragma unroll
    for (int n = 0; n < 4; ++n) {
      int jcol = bcol * 128 + wc * 64 + n * 16 + lr;
      int c2 = jcol & 2047;
      int hh = c2 >> 7, dd = c2 & 127;
#pragma unroll
      for (int m = 0; m < 4; ++m) {
        int i0 = brow * 128 + wr * 64 + m * 16 + g * 4;
        int bb = i0 >> 11, ss = i0 & 2047;
        ushort4 v4;
        v4.x = f2bf(acc[m][n][0]); v4.y = f2bf(acc[m][n][1]);
        v4.z = f2bf(acc[m][n][2]); v4.w = f2bf(acc[m][n][3]);
        *(ushort4*)&vT[(((size_t)(bb * NH + hh)) * HD + dd) * S_LEN + ss] = v4;
      }
    }
  }
}

// ---------------- out-proj GEMM: single-chain bf16 ---------------------------------
__global__ __launch_bounds__(256) void gemm_out_kernel(
    const ushort* __restrict__ Ah, const ushort* __restrict__ Bh,
    float* __restrict__ C) {
  __shared__ ushort ldsA[128 * 64];
  __shared__ ushort ldsB[128 * 64];
  const int t = threadIdx.x;
  const int lane = t & 63, wid = t >> 6;
  int bid = blockIdx.x;                       // 512 blocks (32 brows x 16 bcols)
  int xcd = bid & 7;
  int idx = bid >> 3;                         // 0..63
  int chunk = idx >> 4;                       // 0..3
  int sub = idx & 15;
  const int brow = xcd * 4 + (sub >> 2);
  const int bcol = chunk * 4 + (sub & 3);
  f32x4 acc[4][4];
#pragma unroll
  for (int m = 0; m < 4; ++m)
#pragma unroll
    for (int n = 0; n < 4; ++n) acc[m][n] = (f32x4){0.f, 0.f, 0.f, 0.f};
  gemm_tile_loop(Ah, Bh, brow, bcol, ldsA, ldsB, wid, lane, acc);
  const int g = lane >> 4, lr = lane & 15;
  const int wr = wid >> 1, wc = wid & 1;
#pragma unroll
  for (int m = 0; m < 4; ++m) {
    int i0 = brow * 128 + wr * 64 + m * 16 + g * 4;
#pragma unroll
    for (int n = 0; n < 4; ++n) {
      int jcol = bcol * 128 + wc * 64 + n * 16 + lr;
#pragma unroll
      for (int r = 0; r < 4; ++r)
        C[(size_t)(i0 + r) * DIMM + jcol] = acc[m][n][r];
    }
  }
}

// ---------------- RoPE in-place on bf16 k (q is roped inside attn) -----------------
__global__ __launch_bounds__(256) void rope_k_kernel(
    ushort* __restrict__ k, const int* __restrict__ pid,
    const float* __restrict__ cost, const float* __restrict__ sint) {
  int idx = blockIdx.x * blockDim.x + threadIdx.x;  // B*H*S*16 = 1048576
  int j4 = (idx & 15) * 4;
  int s = (idx >> 4) & 2047;
  int bh = idx >> 15;  // 0..31
  int b = bh >> 4;
  int pos = pid[(b << 11) + s];
  float4 c4 = *(const float4*)&cost[(pos << 6) + j4];
  float4 s4 = *(const float4*)&sint[(pos << 6) + j4];
  float cs[4] = {c4.x, c4.y, c4.z, c4.w};
  float sn[4] = {s4.x, s4.y, s4.z, s4.w};
  size_t base = ((size_t)bh * S_LEN + s) * HD + j4;
  ushort4 lo4 = *(ushort4*)&k[base];
  ushort4 hi4 = *(ushort4*)&k[base + 64];
  ushort* lp = (ushort*)&lo4; ushort* hp = (ushort*)&hi4;
  ushort4 nlo, nhi;
  ushort* nlp = (ushort*)&nlo; ushort* nhp = (ushort*)&nhi;
#pragma unroll
  for (int e = 0; e < 4; ++e) {
    float x1 = bf2f(lp[e]), x2 = bf2f(hp[e]);
    nlp[e] = f2bf(x1 * cs[e] - x2 * sn[e]);
    nhp[e] = f2bf(x2 * cs[e] + x1 * sn[e]);
  }
  *(ushort4*)&k[base] = nlo;
  *(ushort4*)&k[base + 64] = nhi;
}

// ------- bf16 MFMA flash attention: all-gld_lds staging, double-buffer, 1 barrier --
// 4 waves x 32 q-rows; grid 512 XCD-swizzled; fused Q-RoPE; fixed-max softmax.
// V is pre-transposed in global ([bh][d][s]) -> both K and V stage via
// global_load_lds with inverse-swizzled sources; no register staging, no scatter.
// Pipeline: issue next tile's 8 gld_lds -> buf^1; compute tile from buf; barrier.
__global__ __launch_bounds__(256, 2) void attn_mfma_kernel(
    const ushort* __restrict__ qb, const ushort* __restrict__ kb,
    const ushort* __restrict__ vT, const int* __restrict__ pid,
    const float* __restrict__ cost, const float* __restrict__ sint,
    ushort* __restrict__ aoh) {
  __shared__ __align__(16) char lds[65536];  // 2 x {K 16KB [64kj][128d], V 16KB [128d][64kj]}
  const int t = threadIdx.x;
  const int lane = t & 63;
  const int wid = t >> 6;      // 0..3
  const int c31 = lane & 31;
  const int hi = lane >> 5;
  const int bid = blockIdx.x;
  const int j = bid >> 3;
  const int bh = (bid & 7) * 4 + (j >> 4);
  const int q0 = (j & 15) * 128;
  const size_t bhoff = (size_t)bh * S_LEN * HD;
  const ushort* qg = qb + bhoff;
  const ushort* kg = kb + bhoff;
  const ushort* vg = vT + bhoff;   // [d][s] layout within this bh

  // Q fragments with fused RoPE: element (dks,e) = q[qrow][dks*16 + hi*8 + e]
  short8 qf[8];
  {
    int qrow = q0 + wid * 32 + c31;
    int pos = pid[((bh >> 4) << 11) + qrow];
    const float* cb = cost + (pos << 6);
    const float* sb = sint + (pos << 6);
    uint4 raw[8];
#pragma unroll
    for (int dks = 0; dks < 8; ++dks)
      raw[dks] = *(const uint4*)(qg + (size_t)qrow * HD + dks * 16 + hi * 8);
#pragma unroll
    for (int dks = 0; dks < 4; ++dks) {
      int j0 = dks * 16 + hi * 8;
      ushort* lo = (ushort*)&raw[dks];
      ushort* up = (ushort*)&raw[dks + 4];
#pragma unroll
      for (int e = 0; e < 8; ++e) {
        float c = cb[j0 + e], s = sb[j0 + e];
        float x1 = bf2f(lo[e]), x2 = bf2f(up[e]);
        lo[e] = f2bf(x1 * c - x2 * s);
        up[e] = f2bf(x2 * c + x1 * s);
      }
    }
#pragma unroll
    for (int dks = 0; dks < 8; ++dks) qf[dks] = __builtin_bit_cast(short8, raw[dks]);
  }

  f32x16 o[4];
#pragma unroll
  for (int dt = 0; dt < 4; ++dt)
#pragma unroll
    for (int r = 0; r < 16; ++r) o[dt][r] = 0.f;
  float lsum = 0.f;
  const float C1 = 0.08838834764831845f * 1.4426950408889634f;  // log2(e)/sqrt(128)

  // stage K [64][128] (row=kj, 256B) and V^T [128][64] (row=d, 128B) into buf;
  // dest linear, source column pre-swizzled so swizzled reads recover linear data.
  auto stageKV = [&](int kv0, char* buf) {
#pragma unroll
    for (int it = 0; it < 4; ++it) {
      int L = (t + 256 * it) * 16;
      int krow = L >> 8;
      int colb = (L & 255) ^ ((krow & 7) << 4);
      GLD16(kg + (size_t)(kv0 + krow) * HD + (colb >> 1), buf + (L - (lane << 4)));
    }
#pragma unroll
    for (int it = 0; it < 4; ++it) {
      int L = (t + 256 * it) * 16;
      int vrow = L >> 7;
      int colb = (L & 127) ^ ((vrow & 7) << 4);
      GLD16(vg + (size_t)vrow * S_LEN + kv0 + (colb >> 1),
            buf + 16384 + (L - (lane << 4)));
    }
  };

  stageKV(0, lds);
  __syncthreads();  // vmcnt drained by compiler before barrier -> tile 0 ready

#pragma unroll 1
  for (int cc = 0; cc < 32; ++cc) {
    char* cur = lds + (cc & 1) * 32768;
    char* ldsK = cur;
    char* ldsV = cur + 16384;
    if (cc < 31) stageKV((cc + 1) * 64, lds + (((cc & 1) ^ 1) * 32768));

    // ---- QK^T (swapped, 32x32x16): col = qi = c31
    f32x16 s[2];
#pragma unroll
    for (int kjt = 0; kjt < 2; ++kjt) {
#pragma unroll
      for (int r = 0; r < 16; ++r) s[kjt][r] = 0.f;
#pragma unroll
      for (int dks = 0; dks < 8; ++dks) {
        int koff = ((kjt * 32 + c31) * 256 + (32 * dks + 16 * hi)) ^ ((c31 & 7) << 4);
        short8 kf = __builtin_bit_cast(short8, *(const uint4*)(ldsK + koff));
        s[kjt] = __builtin_amdgcn_mfma_f32_32x32x16_bf16(kf, qf[dks], s[kjt], 0, 0, 0);
      }
    }

    // ---- fixed-max softmax + in-register P packing (lane+-32 half-swap)
    float ps = 0.f;
    unsigned paw[4][4];
#pragma unroll
    for (int kjt = 0; kjt < 2; ++kjt) {
      float p[16];
#pragma unroll
      for (int r = 0; r < 16; ++r) {
        p[r] = exp2f(fmaf(s[kjt][r], C1, -2.0f));
        ps += p[r];
      }
#pragma unroll
      for (int hf = 0; hf < 2; ++hf) {
#pragma unroll
        for (int jj = 0; jj < 2; ++jj) {
          unsigned Aw = pk2(p[8 * hf + 2 * jj], p[8 * hf + 2 * jj + 1]);
          unsigned Bw = pk2(p[8 * hf + 4 + 2 * jj], p[8 * hf + 4 + 2 * jj + 1]);
          unsigned tA = __shfl_xor(Aw, 32, 64);
          unsigned tB = __shfl_xor(Bw, 32, 64);
          paw[2 * kjt + hf][jj]     = hi ? tB : Aw;
          paw[2 * kjt + hf][2 + jj] = hi ? Bw : tA;
        }
      }
    }
    ps += __shfl_xor(ps, 32, 64);
    lsum += ps;

    // ---- PV (swapped): O^T[d][qi] += V^T-frag (A) x P-frag (B)
#pragma unroll
    for (int ks = 0; ks < 4; ++ks) {
      uint4 pu = {paw[ks][0], paw[ks][1], paw[ks][2], paw[ks][3]};
      short8 pf = __builtin_bit_cast(short8, pu);
#pragma unroll
      for (int dt = 0; dt < 4; ++dt) {
        int voff = ((32 * dt + c31) * 128 + (32 * ks + 16 * hi)) ^ ((c31 & 7) << 4);
        short8 vf = __builtin_bit_cast(short8, *(const uint4*)(ldsV + voff));
        o[dt] = __builtin_amdgcn_mfma_f32_32x32x16_bf16(vf, pf, o[dt], 0, 0, 0);
      }
    }
    __syncthreads();  // drains next-tile gld_lds (issued ~full compute phase ago)
  }

  // ---- epilogue: lane holds O[d = 32dt + crow(r,hi)][qi = c31]
  const int bb = bh >> 4, hh = bh & 15;
  float inv = 1.0f / lsum;
  int srow = q0 + wid * 32 + c31;
  size_t rbase = ((size_t)(bb * S_LEN + srow)) * DIMM + hh * HD;
#pragma unroll
  for (int dt = 0; dt < 4; ++dt) {
#pragma unroll
    for (int rq = 0; rq < 4; ++rq) {
      int d0 = 32 * dt + 8 * rq + 4 * hi;
      ushort4 h4;
      ushort* hp = (ushort*)&h4;
#pragma unroll
      for (int rr = 0; rr < 4; ++rr)
        hp[rr] = f2bf(o[dt][rq * 4 + rr] * inv);
      *(ushort4*)&aoh[rbase + d0] = h4;
    }
  }
}

extern "C" void kernel_launch(void* const* d_in, const int* in_sizes, int n_in,
                              void* d_out, int out_size, void* d_ws, size_t ws_size,
                              hipStream_t stream) {
  const float* h = (const float*)d_in[0];
  const int* pid = (const int*)d_in[2];
  const float* wq = (const float*)d_in[3];
  const float* wk = (const float*)d_in[4];
  const float* wv = (const float*)d_in[5];
  const float* wo = (const float*)d_in[6];
  float* out = (float*)d_out;

  ushort* qbf = (ushort*)d_ws;                 // q,k: [B,H,S,128] bf16 (contiguous)
  ushort* kbf = qbf + QKV_ELEMS;
  ushort* vT  = kbf + QKV_ELEMS;               // v TRANSPOSED: [B,H,128,S] bf16
  ushort* hbf = vT + QKV_ELEMS;                // [4096][2048] bf16
  ushort* wqb = hbf + QKV_ELEMS;               // [6144][2048] bf16 (wq,wk,wv contiguous)
  ushort* wkb = wqb + (size_t)DIMM * DIMM;
  ushort* wvb = wkb + (size_t)DIMM * DIMM;
  ushort* aoh = wvb + (size_t)DIMM * DIMM;     // [4096][2048] bf16
  ushort* aol = aoh + QKV_ELEMS;               // 16 MB region, reused:
  ushort* woh = aol;                           //   woh = first 8 MB of aol
  float* cost = (float*)(aol + QKV_ELEMS);     // after full aol region -> no overlap
  float* sint = cost + 2048 * 64;

  prep_kernel<<<8192, 256, 0, stream>>>(h, wq, wk, wv, wo, hbf, wqb, wkb, wvb, woh,
                                        cost, sint);
  gemm_qkv_kernel<<<1536, 256, 0, stream>>>(hbf, wqb, qbf, vT);
  rope_k_kernel<<<4096, 256, 0, stream>>>(kbf, pid, cost, sint);
  attn_mfma_kernel<<<512, 256, 0, stream>>>(qbf, kbf, vT, pid, cost, sint, aoh);
  gemm_out_kernel<<<512, 256, 0, stream>>>(aoh, woh, out);
}

// Round 19
// 309.152 us; speedup vs baseline: 1.0395x; 1.0395x over previous
//
#include <hip/hip_runtime.h>
#include <hip/hip_bf16.h>
#include <math.h>

#define S_LEN 2048
#define DIMM 2048
#define NH 16
#define HD 128
#define QKV_ELEMS (2 * NH * S_LEN * HD)   // 8388608 = 4096*2048

typedef __attribute__((ext_vector_type(8))) short short8;
typedef __attribute__((ext_vector_type(4))) float f32x4;
typedef __attribute__((ext_vector_type(16))) float f32x16;

static __device__ __forceinline__ ushort f2bf(float x) {
  union { float f; unsigned u; } v; v.f = x;
  unsigned r = v.u + 0x7fffu + ((v.u >> 16) & 1u);   // RNE
  return (ushort)(r >> 16);
}
static __device__ __forceinline__ float bf2f(ushort u) {
  union { unsigned u; float f; } v; v.u = ((unsigned)u) << 16;
  return v.f;
}
static __device__ __forceinline__ unsigned pk2(float a, float b) {
  return (unsigned)f2bf(a) | ((unsigned)f2bf(b) << 16);  // low = a, high = b
}
static __device__ __forceinline__ f32x4 MF(uint4 a, uint4 b, f32x4 c) {
  return __builtin_amdgcn_mfma_f32_16x16x32_bf16(
      __builtin_bit_cast(short8, a), __builtin_bit_cast(short8, b), c, 0, 0, 0);
}

#define GLD16(gp, lp)                                                        \
  __builtin_amdgcn_global_load_lds(                                          \
      (const __attribute__((address_space(1))) void*)(gp),                   \
      (__attribute__((address_space(3))) void*)(lp), 16, 0, 0)

// ------- fused prep: bf16 casts (h,wq,wk,wv) + wo->bf16 + RoPE table ---------------
__global__ __launch_bounds__(256) void prep_kernel(
    const float* __restrict__ h, const float* __restrict__ wq,
    const float* __restrict__ wk, const float* __restrict__ wv,
    const float* __restrict__ wo,
    ushort* __restrict__ hb, ushort* __restrict__ wqb,
    ushort* __restrict__ wkb, ushort* __restrict__ wvb,
    ushort* __restrict__ woh,
    float* __restrict__ cost, float* __restrict__ sint) {
  const int C_ALL = 5 << 20;      // float4 units: h 2M, wq/wk/wv 1M each
  const int C_WO  = 1 << 20;      // wo float4 units
  const int C_TAB = 32768;        // table: 2048 pos x 16 j-quads
  const int total = C_ALL + C_WO + C_TAB;
  for (int idx = blockIdx.x * 256 + threadIdx.x; idx < total; idx += gridDim.x * 256) {
    if (idx < C_ALL + C_WO) {
      int u = idx >> 20;
      const float* src; ushort* dst; int off;
      if (u < 2)      { src = h;  dst = hb;  off = idx; }
      else if (u == 2){ src = wq; dst = wqb; off = idx - (2 << 20); }
      else if (u == 3){ src = wk; dst = wkb; off = idx - (3 << 20); }
      else if (u == 4){ src = wv; dst = wvb; off = idx - (4 << 20); }
      else            { src = wo; dst = woh; off = idx - (5 << 20); }
      float4 x = ((const float4*)src)[off];
      ushort4 y;
      y.x = f2bf(x.x); y.y = f2bf(x.y); y.z = f2bf(x.z); y.w = f2bf(x.w);
      ((ushort4*)dst)[off] = y;
    } else {
      int r = idx - C_ALL - C_WO;
      int p = r >> 4;
      int j0 = (r & 15) * 4;
#pragma unroll
      for (int e = 0; e < 4; ++e) {
        int j = j0 + e;
        double invf = pow(10000.0, -((double)(2 * j) / 128.0));
        double a = (double)p * invf;
        cost[(p << 6) + j] = (float)cos(a);
        sint[(p << 6) + j] = (float)sin(a);
      }
    }
  }
}

// ---------------- m97-style bf16 NT GEMM core: 128x128 tile, BK=64 -----------------
__device__ __forceinline__ void gemm_tile_loop(
    const ushort* __restrict__ A, const ushort* __restrict__ B,
    int brow, int bcol, ushort* ldsA, ushort* ldsB,
    int wid, int lane, f32x4 (&acc)[4][4]) {
  const int g = lane >> 4, lr = lane & 15;
  const int wr = wid >> 1, wc = wid & 1;
  const int srow = lane >> 3;   // 0..7
  const int slot = lane & 7;    // 16B slot (8 bf16)
  const ushort* Abase = A + ((size_t)(brow * 128 + wid * 32 + srow)) * DIMM + slot * 8;
  const ushort* Bbase = B + ((size_t)(bcol * 128 + wid * 32 + srow)) * DIMM + slot * 8;
  for (int k0 = 0; k0 < DIMM; k0 += 64) {
#pragma unroll
    for (int i = 0; i < 4; ++i) {
      GLD16(Abase + (size_t)i * 8 * DIMM + k0, ldsA + (wid * 4 + i) * 512);
      GLD16(Bbase + (size_t)i * 8 * DIMM + k0, ldsB + (wid * 4 + i) * 512);
    }
    __syncthreads();
    uint4 av[4][2], bv[4][2];
#pragma unroll
    for (int m = 0; m < 4; ++m)
#pragma unroll
      for (int ks = 0; ks < 2; ++ks) {
        av[m][ks] = *(const uint4*)(ldsA + (wr * 64 + m * 16 + lr) * 64 + ks * 32 + g * 8);
        bv[m][ks] = *(const uint4*)(ldsB + (wc * 64 + m * 16 + lr) * 64 + ks * 32 + g * 8);
      }
#pragma unroll
    for (int ks = 0; ks < 2; ++ks)
#pragma unroll
      for (int m = 0; m < 4; ++m)
#pragma unroll
        for (int n = 0; n < 4; ++n)
          acc[m][n] = MF(av[m][ks], bv[n][ks], acc[m][n]);
    __syncthreads();
  }
}

// ---------------- fused QKV projection GEMM: W = [wq;wk;wv] 6144 rows --------------
// Round-17 epilogue verbatim (scattered u16 stores, VGPR 80).
__global__ __launch_bounds__(256) void gemm_qkv_kernel(
    const ushort* __restrict__ A, const ushort* __restrict__ W,
    ushort* __restrict__ dst0) {
  __shared__ ushort ldsA[128 * 64];
  __shared__ ushort ldsB[128 * 64];
  const int t = threadIdx.x;
  const int lane = t & 63, wid = t >> 6;
  int bid = blockIdx.x;                       // 1536 blocks (32 brows x 48 bcols)
  int xcd = bid & 7;
  int idx = bid >> 3;                         // 0..191
  int chunk = idx >> 4;                       // 0..11
  int sub = idx & 15;
  const int brow = xcd * 4 + (sub >> 2);
  const int bcol = chunk * 4 + (sub & 3);
  f32x4 acc[4][4];
#pragma unroll
  for (int m = 0; m < 4; ++m)
#pragma unroll
    for (int n = 0; n < 4; ++n) acc[m][n] = (f32x4){0.f, 0.f, 0.f, 0.f};
  gemm_tile_loop(A, W, brow, bcol, ldsA, ldsB, wid, lane, acc);
  const int g = lane >> 4, lr = lane & 15;
  const int wr = wid >> 1, wc = wid & 1;
#pragma unroll
  for (int n = 0; n < 4; ++n) {
    int jcol = bcol * 128 + wc * 64 + n * 16 + lr;   // 0..6143
    int tensor = jcol >> 11;
    int c2 = jcol & 2047;
    int hh = c2 >> 7, dd = c2 & 127;
    ushort* dst = dst0 + (size_t)tensor * QKV_ELEMS;
#pragma unroll
    for (int m = 0; m < 4; ++m) {
      int i0 = brow * 128 + wr * 64 + m * 16 + g * 4;
#pragma unroll
      for (int r = 0; r < 4; ++r) {
        int tok = i0 + r;
        int bb = tok >> 11, ss = tok & 2047;
        dst[(((size_t)(bb * NH + hh)) * S_LEN + ss) * HD + dd] = f2bf(acc[m][n][r]);
      }
    }
  }
}

// ---------------- V transpose: v [bh][s][128] -> vT [bh][d][2048] ------------------
// 64x64 tiles; LDS swizzle key ((row&7)^((row>>3)&7))<<4 keeps BOTH the b128 row
// writes and the column reads low-conflict.
__global__ __launch_bounds__(256) void transpose_v_kernel(
    const ushort* __restrict__ v, ushort* __restrict__ vT) {
  __shared__ __align__(16) char lt[64 * 128];
  const int t = threadIdx.x;
  int bid = blockIdx.x;           // 32 bh x 32 stile x 2 dtile = 2048
  int bh = bid >> 6;
  int stile = (bid >> 1) & 31;
  int dtile = bid & 1;
  const int s0 = stile * 64, d0 = dtile * 64;
  const ushort* src = v + ((size_t)bh * S_LEN + s0) * HD + d0;
  ushort* dst = vT + ((size_t)bh * HD + d0) * S_LEN + s0;
#pragma unroll
  for (int it = 0; it < 2; ++it) {
    int r = (t >> 3) + 32 * it;      // tile row (s) 0..63
    int c8 = (t & 7) * 8;            // tile col (d) group
    uint4 x = *(const uint4*)(src + (size_t)r * HD + c8);
    int key = (((r & 7) ^ ((r >> 3) & 7)) << 4);
    *(uint4*)(lt + ((r * 128 + c8 * 2) ^ key)) = x;
  }
  __syncthreads();
#pragma unroll
  for (int it = 0; it < 2; ++it) {
    int dr = (t >> 3) + 32 * it;     // tile row of vT (d) 0..63
    int sc8 = (t & 7) * 8;           // s group
    ushort tmp[8];
#pragma unroll
    for (int e = 0; e < 8; ++e) {
      int s = sc8 + e;
      int key = (((s & 7) ^ ((s >> 3) & 7)) << 4);
      tmp[e] = *(const ushort*)(lt + ((s * 128 + dr * 2) ^ key));
    }
    *(uint4*)(dst + (size_t)dr * S_LEN + sc8) = *(uint4*)tmp;
  }
}

// ---------------- out-proj GEMM: single-chain bf16 ---------------------------------
__global__ __launch_bounds__(256) void gemm_out_kernel(
    const ushort* __restrict__ Ah, const ushort* __restrict__ Bh,
    float* __restrict__ C) {
  __shared__ ushort ldsA[128 * 64];
  __shared__ ushort ldsB[128 * 64];
  const int t = threadIdx.x;
  const int lane = t & 63, wid = t >> 6;
  int bid = blockIdx.x;                       // 512 blocks (32 brows x 16 bcols)
  int xcd = bid & 7;
  int idx = bid >> 3;                         // 0..63
  int chunk = idx >> 4;                       // 0..3
  int sub = idx & 15;
  const int brow = xcd * 4 + (sub >> 2);
  const int bcol = chunk * 4 + (sub & 3);
  f32x4 acc[4][4];
#pragma unroll
  for (int m = 0; m < 4; ++m)
#pragma unroll
    for (int n = 0; n < 4; ++n) acc[m][n] = (f32x4){0.f, 0.f, 0.f, 0.f};
  gemm_tile_loop(Ah, Bh, brow, bcol, ldsA, ldsB, wid, lane, acc);
  const int g = lane >> 4, lr = lane & 15;
  const int wr = wid >> 1, wc = wid & 1;
#pragma unroll
  for (int m = 0; m < 4; ++m) {
    int i0 = brow * 128 + wr * 64 + m * 16 + g * 4;
#pragma unroll
    for (int n = 0; n < 4; ++n) {
      int jcol = bcol * 128 + wc * 64 + n * 16 + lr;
#pragma unroll
      for (int r = 0; r < 4; ++r)
        C[(size_t)(i0 + r) * DIMM + jcol] = acc[m][n][r];
    }
  }
}

// ---------------- RoPE in-place on bf16 k (q is roped inside attn) -----------------
__global__ __launch_bounds__(256) void rope_k_kernel(
    ushort* __restrict__ k, const int* __restrict__ pid,
    const float* __restrict__ cost, const float* __restrict__ sint) {
  int idx = blockIdx.x * blockDim.x + threadIdx.x;  // B*H*S*16 = 1048576
  int j4 = (idx & 15) * 4;
  int s = (idx >> 4) & 2047;
  int bh = idx >> 15;  // 0..31
  int b = bh >> 4;
  int pos = pid[(b << 11) + s];
  float4 c4 = *(const float4*)&cost[(pos << 6) + j4];
  float4 s4 = *(const float4*)&sint[(pos << 6) + j4];
  float cs[4] = {c4.x, c4.y, c4.z, c4.w};
  float sn[4] = {s4.x, s4.y, s4.z, s4.w};
  size_t base = ((size_t)bh * S_LEN + s) * HD + j4;
  ushort4 lo4 = *(ushort4*)&k[base];
  ushort4 hi4 = *(ushort4*)&k[base + 64];
  ushort* lp = (ushort*)&lo4; ushort* hp = (ushort*)&hi4;
  ushort4 nlo, nhi;
  ushort* nlp = (ushort*)&nlo; ushort* nhp = (ushort*)&nhi;
#pragma unroll
  for (int e = 0; e < 4; ++e) {
    float x1 = bf2f(lp[e]), x2 = bf2f(hp[e]);
    nlp[e] = f2bf(x1 * cs[e] - x2 * sn[e]);
    nhp[e] = f2bf(x2 * cs[e] + x1 * sn[e]);
  }
  *(ushort4*)&k[base] = nlo;
  *(ushort4*)&k[base + 64] = nhi;
}

// ------- bf16 MFMA flash attention: all-gld_lds staging, double-buffer, 1 barrier --
// (round-18 verified; V pre-transposed in global)
__global__ __launch_bounds__(256, 2) void attn_mfma_kernel(
    const ushort* __restrict__ qb, const ushort* __restrict__ kb,
    const ushort* __restrict__ vT, const int* __restrict__ pid,
    const float* __restrict__ cost, const float* __restrict__ sint,
    ushort* __restrict__ aoh) {
  __shared__ __align__(16) char lds[65536];  // 2 x {K 16KB [64kj][128d], V 16KB [128d][64kj]}
  const int t = threadIdx.x;
  const int lane = t & 63;
  const int wid = t >> 6;      // 0..3
  const int c31 = lane & 31;
  const int hi = lane >> 5;
  const int bid = blockIdx.x;
  const int j = bid >> 3;
  const int bh = (bid & 7) * 4 + (j >> 4);
  const int q0 = (j & 15) * 128;
  const size_t bhoff = (size_t)bh * S_LEN * HD;
  const ushort* qg = qb + bhoff;
  const ushort* kg = kb + bhoff;
  const ushort* vg = vT + bhoff;   // [d][s] layout within this bh

  // Q fragments with fused RoPE: element (dks,e) = q[qrow][dks*16 + hi*8 + e]
  short8 qf[8];
  {
    int qrow = q0 + wid * 32 + c31;
    int pos = pid[((bh >> 4) << 11) + qrow];
    const float* cb = cost + (pos << 6);
    const float* sb = sint + (pos << 6);
    uint4 raw[8];
#pragma unroll
    for (int dks = 0; dks < 8; ++dks)
      raw[dks] = *(const uint4*)(qg + (size_t)qrow * HD + dks * 16 + hi * 8);
#pragma unroll
    for (int dks = 0; dks < 4; ++dks) {
      int j0 = dks * 16 + hi * 8;
      ushort* lo = (ushort*)&raw[dks];
      ushort* up = (ushort*)&raw[dks + 4];
#pragma unroll
      for (int e = 0; e < 8; ++e) {
        float c = cb[j0 + e], s = sb[j0 + e];
        float x1 = bf2f(lo[e]), x2 = bf2f(up[e]);
        lo[e] = f2bf(x1 * c - x2 * s);
        up[e] = f2bf(x2 * c + x1 * s);
      }
    }
#pragma unroll
    for (int dks = 0; dks < 8; ++dks) qf[dks] = __builtin_bit_cast(short8, raw[dks]);
  }

  f32x16 o[4];
#pragma unroll
  for (int dt = 0; dt < 4; ++dt)
#pragma unroll
    for (int r = 0; r < 16; ++r) o[dt][r] = 0.f;
  float lsum = 0.f;
  const float C1 = 0.08838834764831845f * 1.4426950408889634f;  // log2(e)/sqrt(128)

  auto stageKV = [&](int kv0, char* buf) {
#pragma unroll
    for (int it = 0; it < 4; ++it) {
      int L = (t + 256 * it) * 16;
      int krow = L >> 8;
      int colb = (L & 255) ^ ((krow & 7) << 4);
      GLD16(kg + (size_t)(kv0 + krow) * HD + (colb >> 1), buf + (L - (lane << 4)));
    }
#pragma unroll
    for (int it = 0; it < 4; ++it) {
      int L = (t + 256 * it) * 16;
      int vrow = L >> 7;
      int colb = (L & 127) ^ ((vrow & 7) << 4);
      GLD16(vg + (size_t)vrow * S_LEN + kv0 + (colb >> 1),
            buf + 16384 + (L - (lane << 4)));
    }
  };

  stageKV(0, lds);
  __syncthreads();

#pragma unroll 1
  for (int cc = 0; cc < 32; ++cc) {
    char* cur = lds + (cc & 1) * 32768;
    char* ldsK = cur;
    char* ldsV = cur + 16384;
    if (cc < 31) stageKV((cc + 1) * 64, lds + (((cc & 1) ^ 1) * 32768));

    f32x16 s[2];
#pragma unroll
    for (int kjt = 0; kjt < 2; ++kjt) {
#pragma unroll
      for (int r = 0; r < 16; ++r) s[kjt][r] = 0.f;
#pragma unroll
      for (int dks = 0; dks < 8; ++dks) {
        int koff = ((kjt * 32 + c31) * 256 + (32 * dks + 16 * hi)) ^ ((c31 & 7) << 4);
        short8 kf = __builtin_bit_cast(short8, *(const uint4*)(ldsK + koff));
        s[kjt] = __builtin_amdgcn_mfma_f32_32x32x16_bf16(kf, qf[dks], s[kjt], 0, 0, 0);
      }
    }

    float ps = 0.f;
    unsigned paw[4][4];
#pragma unroll
    for (int kjt = 0; kjt < 2; ++kjt) {
      float p[16];
#pragma unroll
      for (int r = 0; r < 16; ++r) {
        p[r] = exp2f(fmaf(s[kjt][r], C1, -2.0f));
        ps += p[r];
      }
#pragma unroll
      for (int hf = 0; hf < 2; ++hf) {
#pragma unroll
        for (int jj = 0; jj < 2; ++jj) {
          unsigned Aw = pk2(p[8 * hf + 2 * jj], p[8 * hf + 2 * jj + 1]);
          unsigned Bw = pk2(p[8 * hf + 4 + 2 * jj], p[8 * hf + 4 + 2 * jj + 1]);
          unsigned tA = __shfl_xor(Aw, 32, 64);
          unsigned tB = __shfl_xor(Bw, 32, 64);
          paw[2 * kjt + hf][jj]     = hi ? tB : Aw;
          paw[2 * kjt + hf][2 + jj] = hi ? Bw : tA;
        }
      }
    }
    ps += __shfl_xor(ps, 32, 64);
    lsum += ps;

#pragma unroll
    for (int ks = 0; ks < 4; ++ks) {
      uint4 pu = {paw[ks][0], paw[ks][1], paw[ks][2], paw[ks][3]};
      short8 pf = __builtin_bit_cast(short8, pu);
#pragma unroll
      for (int dt = 0; dt < 4; ++dt) {
        int voff = ((32 * dt + c31) * 128 + (32 * ks + 16 * hi)) ^ ((c31 & 7) << 4);
        short8 vf = __builtin_bit_cast(short8, *(const uint4*)(ldsV + voff));
        o[dt] = __builtin_amdgcn_mfma_f32_32x32x16_bf16(vf, pf, o[dt], 0, 0, 0);
      }
    }
    __syncthreads();
  }

  const int bb = bh >> 4, hh = bh & 15;
  float inv = 1.0f / lsum;
  int srow = q0 + wid * 32 + c31;
  size_t rbase = ((size_t)(bb * S_LEN + srow)) * DIMM + hh * HD;
#pragma unroll
  for (int dt = 0; dt < 4; ++dt) {
#pragma unroll
    for (int rq = 0; rq < 4; ++rq) {
      int d0 = 32 * dt + 8 * rq + 4 * hi;
      ushort4 h4;
      ushort* hp = (ushort*)&h4;
#pragma unroll
      for (int rr = 0; rr < 4; ++rr)
        hp[rr] = f2bf(o[dt][rq * 4 + rr] * inv);
      *(ushort4*)&aoh[rbase + d0] = h4;
    }
  }
}

extern "C" void kernel_launch(void* const* d_in, const int* in_sizes, int n_in,
                              void* d_out, int out_size, void* d_ws, size_t ws_size,
                              hipStream_t stream) {
  const float* h = (const float*)d_in[0];
  const int* pid = (const int*)d_in[2];
  const float* wq = (const float*)d_in[3];
  const float* wk = (const float*)d_in[4];
  const float* wv = (const float*)d_in[5];
  const float* wo = (const float*)d_in[6];
  float* out = (float*)d_out;

  ushort* qbf = (ushort*)d_ws;                 // q,k,v: [B,H,S,128] bf16 (contiguous)
  ushort* kbf = qbf + QKV_ELEMS;
  ushort* vbf = kbf + QKV_ELEMS;
  ushort* hbf = vbf + QKV_ELEMS;               // [4096][2048] bf16; becomes vT after qkv
  ushort* wqb = hbf + QKV_ELEMS;               // [6144][2048] bf16 (wq,wk,wv contiguous)
  ushort* wkb = wqb + (size_t)DIMM * DIMM;
  ushort* wvb = wkb + (size_t)DIMM * DIMM;
  ushort* aoh = wvb + (size_t)DIMM * DIMM;     // [4096][2048] bf16
  ushort* aol = aoh + QKV_ELEMS;               // 16 MB region, reused:
  ushort* woh = aol;                           //   woh = first 8 MB of aol
  float* cost = (float*)(aol + QKV_ELEMS);     // after full aol region -> no overlap
  float* sint = cost + 2048 * 64;
  ushort* vT = hbf;                            // overlay: hbf dead after gemm_qkv

  prep_kernel<<<8192, 256, 0, stream>>>(h, wq, wk, wv, wo, hbf, wqb, wkb, wvb, woh,
                                        cost, sint);
  gemm_qkv_kernel<<<1536, 256, 0, stream>>>(hbf, wqb, qbf);
  transpose_v_kernel<<<2048, 256, 0, stream>>>(vbf, vT);
  rope_k_kernel<<<4096, 256, 0, stream>>>(kbf, pid, cost, sint);
  attn_mfma_kernel<<<512, 256, 0, stream>>>(qbf, kbf, vT, pid, cost, sint, aoh);
  gemm_out_kernel<<<512, 256, 0, stream>>>(aoh, woh, out);
}

// Round 20
// 301.160 us; speedup vs baseline: 1.0671x; 1.0265x over previous
//
#include <hip/hip_runtime.h>
#include <hip/hip_bf16.h>
#include <math.h>

#define S_LEN 2048
#define DIMM 2048
#define NH 16
#define HD 128
#define QKV_ELEMS (2 * NH * S_LEN * HD)   // 8388608 = 4096*2048

typedef __attribute__((ext_vector_type(8))) short short8;
typedef __attribute__((ext_vector_type(4))) float f32x4;
typedef __attribute__((ext_vector_type(16))) float f32x16;

static __device__ __forceinline__ ushort f2bf(float x) {
  union { float f; unsigned u; } v; v.f = x;
  unsigned r = v.u + 0x7fffu + ((v.u >> 16) & 1u);   // RNE
  return (ushort)(r >> 16);
}
static __device__ __forceinline__ float bf2f(ushort u) {
  union { unsigned u; float f; } v; v.u = ((unsigned)u) << 16;
  return v.f;
}
static __device__ __forceinline__ unsigned pk2(float a, float b) {
  return (unsigned)f2bf(a) | ((unsigned)f2bf(b) << 16);  // low = a, high = b
}
static __device__ __forceinline__ f32x4 MF(uint4 a, uint4 b, f32x4 c) {
  return __builtin_amdgcn_mfma_f32_16x16x32_bf16(
      __builtin_bit_cast(short8, a), __builtin_bit_cast(short8, b), c, 0, 0, 0);
}

#define GLD16(gp, lp)                                                        \
  __builtin_amdgcn_global_load_lds(                                          \
      (const __attribute__((address_space(1))) void*)(gp),                   \
      (__attribute__((address_space(3))) void*)(lp), 16, 0, 0)

// ------- fused prep: bf16 casts (h,wq,wk,wv) + wo->bf16 + RoPE table ---------------
__global__ __launch_bounds__(256) void prep_kernel(
    const float* __restrict__ h, const float* __restrict__ wq,
    const float* __restrict__ wk, const float* __restrict__ wv,
    const float* __restrict__ wo,
    ushort* __restrict__ hb, ushort* __restrict__ wqb,
    ushort* __restrict__ wkb, ushort* __restrict__ wvb,
    ushort* __restrict__ woh,
    float* __restrict__ cost, float* __restrict__ sint) {
  const int C_ALL = 5 << 20;      // float4 units: h 2M, wq/wk/wv 1M each
  const int C_WO  = 1 << 20;      // wo float4 units
  const int C_TAB = 32768;        // table: 2048 pos x 16 j-quads
  const int total = C_ALL + C_WO + C_TAB;
  for (int idx = blockIdx.x * 256 + threadIdx.x; idx < total; idx += gridDim.x * 256) {
    if (idx < C_ALL + C_WO) {
      int u = idx >> 20;
      const float* src; ushort* dst; int off;
      if (u < 2)      { src = h;  dst = hb;  off = idx; }
      else if (u == 2){ src = wq; dst = wqb; off = idx - (2 << 20); }
      else if (u == 3){ src = wk; dst = wkb; off = idx - (3 << 20); }
      else if (u == 4){ src = wv; dst = wvb; off = idx - (4 << 20); }
      else            { src = wo; dst = woh; off = idx - (5 << 20); }
      float4 x = ((const float4*)src)[off];
      ushort4 y;
      y.x = f2bf(x.x); y.y = f2bf(x.y); y.z = f2bf(x.z); y.w = f2bf(x.w);
      ((ushort4*)dst)[off] = y;
    } else {
      int r = idx - C_ALL - C_WO;
      int p = r >> 4;
      int j0 = (r & 15) * 4;
#pragma unroll
      for (int e = 0; e < 4; ++e) {
        int j = j0 + e;
        double invf = pow(10000.0, -((double)(2 * j) / 128.0));
        double a = (double)p * invf;
        cost[(p << 6) + j] = (float)cos(a);
        sint[(p << 6) + j] = (float)sin(a);
      }
    }
  }
}

// ------- bf16 NT GEMM core: 128x128 tile, BK=64, double-buffered LDS, 1 barrier ----
// T3-minimal: issue stage(buf^1, t+1) BEFORE compute(buf); single barrier per K-step
// (its implicit vmcnt(0) drain lands a full compute-phase after the issue).
__device__ __forceinline__ void gemm_tile_loop(
    const ushort* __restrict__ A, const ushort* __restrict__ B,
    int brow, int bcol, ushort* ldsA0, ushort* ldsB0,
    ushort* ldsA1, ushort* ldsB1,
    int wid, int lane, f32x4 (&acc)[4][4]) {
  const int g = lane >> 4, lr = lane & 15;
  const int wr = wid >> 1, wc = wid & 1;
  const int srow = lane >> 3;   // 0..7
  const int slot = lane & 7;    // 16B slot (8 bf16)
  const ushort* Abase = A + ((size_t)(brow * 128 + wid * 32 + srow)) * DIMM + slot * 8;
  const ushort* Bbase = B + ((size_t)(bcol * 128 + wid * 32 + srow)) * DIMM + slot * 8;
  auto stage = [&](int k0, ushort* dA, ushort* dB) {
#pragma unroll
    for (int i = 0; i < 4; ++i) {
      GLD16(Abase + (size_t)i * 8 * DIMM + k0, dA + (wid * 4 + i) * 512);
      GLD16(Bbase + (size_t)i * 8 * DIMM + k0, dB + (wid * 4 + i) * 512);
    }
  };
  stage(0, ldsA0, ldsB0);
  __syncthreads();  // compiler drains vmcnt before barrier -> buf0 ready
#pragma unroll 1
  for (int k0 = 0; k0 < DIMM; k0 += 64) {
    ushort* cA = (k0 & 64) ? ldsA1 : ldsA0;
    ushort* cB = (k0 & 64) ? ldsB1 : ldsB0;
    if (k0 + 64 < DIMM)
      stage(k0 + 64, (k0 & 64) ? ldsA0 : ldsA1, (k0 & 64) ? ldsB0 : ldsB1);
    uint4 av[4][2], bv[4][2];
#pragma unroll
    for (int m = 0; m < 4; ++m)
#pragma unroll
      for (int ks = 0; ks < 2; ++ks) {
        av[m][ks] = *(const uint4*)(cA + (wr * 64 + m * 16 + lr) * 64 + ks * 32 + g * 8);
        bv[m][ks] = *(const uint4*)(cB + (wc * 64 + m * 16 + lr) * 64 + ks * 32 + g * 8);
      }
#pragma unroll
    for (int ks = 0; ks < 2; ++ks)
#pragma unroll
      for (int m = 0; m < 4; ++m)
#pragma unroll
        for (int n = 0; n < 4; ++n)
          acc[m][n] = MF(av[m][ks], bv[n][ks], acc[m][n]);
    __syncthreads();  // drains next-tile gld_lds (issued before compute) + publishes
  }
}

// ---------------- fused QKV projection GEMM: W = [wq;wk;wv] 6144 rows --------------
__global__ __launch_bounds__(256) void gemm_qkv_kernel(
    const ushort* __restrict__ A, const ushort* __restrict__ W,
    ushort* __restrict__ dst0) {
  __shared__ ushort ldsA0[128 * 64];
  __shared__ ushort ldsB0[128 * 64];
  __shared__ ushort ldsA1[128 * 64];
  __shared__ ushort ldsB1[128 * 64];
  const int t = threadIdx.x;
  const int lane = t & 63, wid = t >> 6;
  int bid = blockIdx.x;                       // 1536 blocks (32 brows x 48 bcols)
  int xcd = bid & 7;
  int idx = bid >> 3;                         // 0..191
  int chunk = idx >> 4;                       // 0..11
  int sub = idx & 15;
  const int brow = xcd * 4 + (sub >> 2);
  const int bcol = chunk * 4 + (sub & 3);
  f32x4 acc[4][4];
#pragma unroll
  for (int m = 0; m < 4; ++m)
#pragma unroll
    for (int n = 0; n < 4; ++n) acc[m][n] = (f32x4){0.f, 0.f, 0.f, 0.f};
  gemm_tile_loop(A, W, brow, bcol, ldsA0, ldsB0, ldsA1, ldsB1, wid, lane, acc);
  const int g = lane >> 4, lr = lane & 15;
  const int wr = wid >> 1, wc = wid & 1;
#pragma unroll
  for (int n = 0; n < 4; ++n) {
    int jcol = bcol * 128 + wc * 64 + n * 16 + lr;   // 0..6143
    int tensor = jcol >> 11;
    int c2 = jcol & 2047;
    int hh = c2 >> 7, dd = c2 & 127;
    ushort* dst = dst0 + (size_t)tensor * QKV_ELEMS;
#pragma unroll
    for (int m = 0; m < 4; ++m) {
      int i0 = brow * 128 + wr * 64 + m * 16 + g * 4;
#pragma unroll
      for (int r = 0; r < 4; ++r) {
        int tok = i0 + r;
        int bb = tok >> 11, ss = tok & 2047;
        dst[(((size_t)(bb * NH + hh)) * S_LEN + ss) * HD + dd] = f2bf(acc[m][n][r]);
      }
    }
  }
}

// ---------------- V transpose: v [bh][s][128] -> vT [bh][d][2048] ------------------
__global__ __launch_bounds__(256) void transpose_v_kernel(
    const ushort* __restrict__ v, ushort* __restrict__ vT) {
  __shared__ __align__(16) char lt[64 * 128];
  const int t = threadIdx.x;
  int bid = blockIdx.x;           // 32 bh x 32 stile x 2 dtile = 2048
  int bh = bid >> 6;
  int stile = (bid >> 1) & 31;
  int dtile = bid & 1;
  const int s0 = stile * 64, d0 = dtile * 64;
  const ushort* src = v + ((size_t)bh * S_LEN + s0) * HD + d0;
  ushort* dst = vT + ((size_t)bh * HD + d0) * S_LEN + s0;
#pragma unroll
  for (int it = 0; it < 2; ++it) {
    int r = (t >> 3) + 32 * it;      // tile row (s) 0..63
    int c8 = (t & 7) * 8;            // tile col (d) group
    uint4 x = *(const uint4*)(src + (size_t)r * HD + c8);
    int key = (((r & 7) ^ ((r >> 3) & 7)) << 4);
    *(uint4*)(lt + ((r * 128 + c8 * 2) ^ key)) = x;
  }
  __syncthreads();
#pragma unroll
  for (int it = 0; it < 2; ++it) {
    int dr = (t >> 3) + 32 * it;     // tile row of vT (d) 0..63
    int sc8 = (t & 7) * 8;           // s group
    ushort tmp[8];
#pragma unroll
    for (int e = 0; e < 8; ++e) {
      int s = sc8 + e;
      int key = (((s & 7) ^ ((s >> 3) & 7)) << 4);
      tmp[e] = *(const ushort*)(lt + ((s * 128 + dr * 2) ^ key));
    }
    *(uint4*)(dst + (size_t)dr * S_LEN + sc8) = *(uint4*)tmp;
  }
}

// ---------------- out-proj GEMM: single-chain bf16 ---------------------------------
__global__ __launch_bounds__(256) void gemm_out_kernel(
    const ushort* __restrict__ Ah, const ushort* __restrict__ Bh,
    float* __restrict__ C) {
  __shared__ ushort ldsA0[128 * 64];
  __shared__ ushort ldsB0[128 * 64];
  __shared__ ushort ldsA1[128 * 64];
  __shared__ ushort ldsB1[128 * 64];
  const int t = threadIdx.x;
  const int lane = t & 63, wid = t >> 6;
  int bid = blockIdx.x;                       // 512 blocks (32 brows x 16 bcols)
  int xcd = bid & 7;
  int idx = bid >> 3;                         // 0..63
  int chunk = idx >> 4;                       // 0..3
  int sub = idx & 15;
  const int brow = xcd * 4 + (sub >> 2);
  const int bcol = chunk * 4 + (sub & 3);
  f32x4 acc[4][4];
#pragma unroll
  for (int m = 0; m < 4; ++m)
#pragma unroll
    for (int n = 0; n < 4; ++n) acc[m][n] = (f32x4){0.f, 0.f, 0.f, 0.f};
  gemm_tile_loop(Ah, Bh, brow, bcol, ldsA0, ldsB0, ldsA1, ldsB1, wid, lane, acc);
  const int g = lane >> 4, lr = lane & 15;
  const int wr = wid >> 1, wc = wid & 1;
#pragma unroll
  for (int m = 0; m < 4; ++m) {
    int i0 = brow * 128 + wr * 64 + m * 16 + g * 4;
#pragma unroll
    for (int n = 0; n < 4; ++n) {
      int jcol = bcol * 128 + wc * 64 + n * 16 + lr;
#pragma unroll
      for (int r = 0; r < 4; ++r)
        C[(size_t)(i0 + r) * DIMM + jcol] = acc[m][n][r];
    }
  }
}

// ---------------- RoPE in-place on bf16 k (q is roped inside attn) -----------------
__global__ __launch_bounds__(256) void rope_k_kernel(
    ushort* __restrict__ k, const int* __restrict__ pid,
    const float* __restrict__ cost, const float* __restrict__ sint) {
  int idx = blockIdx.x * blockDim.x + threadIdx.x;  // B*H*S*16 = 1048576
  int j4 = (idx & 15) * 4;
  int s = (idx >> 4) & 2047;
  int bh = idx >> 15;  // 0..31
  int b = bh >> 4;
  int pos = pid[(b << 11) + s];
  float4 c4 = *(const float4*)&cost[(pos << 6) + j4];
  float4 s4 = *(const float4*)&sint[(pos << 6) + j4];
  float cs[4] = {c4.x, c4.y, c4.z, c4.w};
  float sn[4] = {s4.x, s4.y, s4.z, s4.w};
  size_t base = ((size_t)bh * S_LEN + s) * HD + j4;
  ushort4 lo4 = *(ushort4*)&k[base];
  ushort4 hi4 = *(ushort4*)&k[base + 64];
  ushort* lp = (ushort*)&lo4; ushort* hp = (ushort*)&hi4;
  ushort4 nlo, nhi;
  ushort* nlp = (ushort*)&nlo; ushort* nhp = (ushort*)&nhi;
#pragma unroll
  for (int e = 0; e < 4; ++e) {
    float x1 = bf2f(lp[e]), x2 = bf2f(hp[e]);
    nlp[e] = f2bf(x1 * cs[e] - x2 * sn[e]);
    nhp[e] = f2bf(x2 * cs[e] + x1 * sn[e]);
  }
  *(ushort4*)&k[base] = nlo;
  *(ushort4*)&k[base + 64] = nhi;
}

// ------- bf16 MFMA flash attention: all-gld_lds staging, double-buffer, 1 barrier --
// (round-18/19 verified; V pre-transposed in global)
__global__ __launch_bounds__(256, 2) void attn_mfma_kernel(
    const ushort* __restrict__ qb, const ushort* __restrict__ kb,
    const ushort* __restrict__ vT, const int* __restrict__ pid,
    const float* __restrict__ cost, const float* __restrict__ sint,
    ushort* __restrict__ aoh) {
  __shared__ __align__(16) char lds[65536];  // 2 x {K 16KB [64kj][128d], V 16KB [128d][64kj]}
  const int t = threadIdx.x;
  const int lane = t & 63;
  const int wid = t >> 6;      // 0..3
  const int c31 = lane & 31;
  const int hi = lane >> 5;
  const int bid = blockIdx.x;
  const int j = bid >> 3;
  const int bh = (bid & 7) * 4 + (j >> 4);
  const int q0 = (j & 15) * 128;
  const size_t bhoff = (size_t)bh * S_LEN * HD;
  const ushort* qg = qb + bhoff;
  const ushort* kg = kb + bhoff;
  const ushort* vg = vT + bhoff;   // [d][s] layout within this bh

  short8 qf[8];
  {
    int qrow = q0 + wid * 32 + c31;
    int pos = pid[((bh >> 4) << 11) + qrow];
    const float* cb = cost + (pos << 6);
    const float* sb = sint + (pos << 6);
    uint4 raw[8];
#pragma unroll
    for (int dks = 0; dks < 8; ++dks)
      raw[dks] = *(const uint4*)(qg + (size_t)qrow * HD + dks * 16 + hi * 8);
#pragma unroll
    for (int dks = 0; dks < 4; ++dks) {
      int j0 = dks * 16 + hi * 8;
      ushort* lo = (ushort*)&raw[dks];
      ushort* up = (ushort*)&raw[dks + 4];
#pragma unroll
      for (int e = 0; e < 8; ++e) {
        float c = cb[j0 + e], s = sb[j0 + e];
        float x1 = bf2f(lo[e]), x2 = bf2f(up[e]);
        lo[e] = f2bf(x1 * c - x2 * s);
        up[e] = f2bf(x2 * c + x1 * s);
      }
    }
#pragma unroll
    for (int dks = 0; dks < 8; ++dks) qf[dks] = __builtin_bit_cast(short8, raw[dks]);
  }

  f32x16 o[4];
#pragma unroll
  for (int dt = 0; dt < 4; ++dt)
#pragma unroll
    for (int r = 0; r < 16; ++r) o[dt][r] = 0.f;
  float lsum = 0.f;
  const float C1 = 0.08838834764831845f * 1.4426950408889634f;  // log2(e)/sqrt(128)

  auto stageKV = [&](int kv0, char* buf) {
#pragma unroll
    for (int it = 0; it < 4; ++it) {
      int L = (t + 256 * it) * 16;
      int krow = L >> 8;
      int colb = (L & 255) ^ ((krow & 7) << 4);
      GLD16(kg + (size_t)(kv0 + krow) * HD + (colb >> 1), buf + (L - (lane << 4)));
    }
#pragma unroll
    for (int it = 0; it < 4; ++it) {
      int L = (t + 256 * it) * 16;
      int vrow = L >> 7;
      int colb = (L & 127) ^ ((vrow & 7) << 4);
      GLD16(vg + (size_t)vrow * S_LEN + kv0 + (colb >> 1),
            buf + 16384 + (L - (lane << 4)));
    }
  };

  stageKV(0, lds);
  __syncthreads();

#pragma unroll 1
  for (int cc = 0; cc < 32; ++cc) {
    char* cur = lds + (cc & 1) * 32768;
    char* ldsK = cur;
    char* ldsV = cur + 16384;
    if (cc < 31) stageKV((cc + 1) * 64, lds + (((cc & 1) ^ 1) * 32768));

    f32x16 s[2];
#pragma unroll
    for (int kjt = 0; kjt < 2; ++kjt) {
#pragma unroll
      for (int r = 0; r < 16; ++r) s[kjt][r] = 0.f;
#pragma unroll
      for (int dks = 0; dks < 8; ++dks) {
        int koff = ((kjt * 32 + c31) * 256 + (32 * dks + 16 * hi)) ^ ((c31 & 7) << 4);
        short8 kf = __builtin_bit_cast(short8, *(const uint4*)(ldsK + koff));
        s[kjt] = __builtin_amdgcn_mfma_f32_32x32x16_bf16(kf, qf[dks], s[kjt], 0, 0, 0);
      }
    }

    float ps = 0.f;
    unsigned paw[4][4];
#pragma unroll
    for (int kjt = 0; kjt < 2; ++kjt) {
      float p[16];
#pragma unroll
      for (int r = 0; r < 16; ++r) {
        p[r] = exp2f(fmaf(s[kjt][r], C1, -2.0f));
        ps += p[r];
      }
#pragma unroll
      for (int hf = 0; hf < 2; ++hf) {
#pragma unroll
        for (int jj = 0; jj < 2; ++jj) {
          unsigned Aw = pk2(p[8 * hf + 2 * jj], p[8 * hf + 2 * jj + 1]);
          unsigned Bw = pk2(p[8 * hf + 4 + 2 * jj], p[8 * hf + 4 + 2 * jj + 1]);
          unsigned tA = __shfl_xor(Aw, 32, 64);
          unsigned tB = __shfl_xor(Bw, 32, 64);
          paw[2 * kjt + hf][jj]     = hi ? tB : Aw;
          paw[2 * kjt + hf][2 + jj] = hi ? Bw : tA;
        }
      }
    }
    ps += __shfl_xor(ps, 32, 64);
    lsum += ps;

#pragma unroll
    for (int ks = 0; ks < 4; ++ks) {
      uint4 pu = {paw[ks][0], paw[ks][1], paw[ks][2], paw[ks][3]};
      short8 pf = __builtin_bit_cast(short8, pu);
#pragma unroll
      for (int dt = 0; dt < 4; ++dt) {
        int voff = ((32 * dt + c31) * 128 + (32 * ks + 16 * hi)) ^ ((c31 & 7) << 4);
        short8 vf = __builtin_bit_cast(short8, *(const uint4*)(ldsV + voff));
        o[dt] = __builtin_amdgcn_mfma_f32_32x32x16_bf16(vf, pf, o[dt], 0, 0, 0);
      }
    }
    __syncthreads();
  }

  const int bb = bh >> 4, hh = bh & 15;
  float inv = 1.0f / lsum;
  int srow = q0 + wid * 32 + c31;
  size_t rbase = ((size_t)(bb * S_LEN + srow)) * DIMM + hh * HD;
#pragma unroll
  for (int dt = 0; dt < 4; ++dt) {
#pragma unroll
    for (int rq = 0; rq < 4; ++rq) {
      int d0 = 32 * dt + 8 * rq + 4 * hi;
      ushort4 h4;
      ushort* hp = (ushort*)&h4;
#pragma unroll
      for (int rr = 0; rr < 4; ++rr)
        hp[rr] = f2bf(o[dt][rq * 4 + rr] * inv);
      *(ushort4*)&aoh[rbase + d0] = h4;
    }
  }
}

extern "C" void kernel_launch(void* const* d_in, const int* in_sizes, int n_in,
                              void* d_out, int out_size, void* d_ws, size_t ws_size,
                              hipStream_t stream) {
  const float* h = (const float*)d_in[0];
  const int* pid = (const int*)d_in[2];
  const float* wq = (const float*)d_in[3];
  const float* wk = (const float*)d_in[4];
  const float* wv = (const float*)d_in[5];
  const float* wo = (const float*)d_in[6];
  float* out = (float*)d_out;

  ushort* qbf = (ushort*)d_ws;                 // q,k,v: [B,H,S,128] bf16 (contiguous)
  ushort* kbf = qbf + QKV_ELEMS;
  ushort* vbf = kbf + QKV_ELEMS;
  ushort* hbf = vbf + QKV_ELEMS;               // [4096][2048] bf16; becomes vT after qkv
  ushort* wqb = hbf + QKV_ELEMS;               // [6144][2048] bf16 (wq,wk,wv contiguous)
  ushort* wkb = wqb + (size_t)DIMM * DIMM;
  ushort* wvb = wkb + (size_t)DIMM * DIMM;
  ushort* aoh = wvb + (size_t)DIMM * DIMM;     // [4096][2048] bf16
  ushort* aol = aoh + QKV_ELEMS;               // 16 MB region, reused:
  ushort* woh = aol;                           //   woh = first 8 MB of aol
  float* cost = (float*)(aol + QKV_ELEMS);     // after full aol region -> no overlap
  float* sint = cost + 2048 * 64;
  ushort* vT = hbf;                            // overlay: hbf dead after gemm_qkv

  prep_kernel<<<8192, 256, 0, stream>>>(h, wq, wk, wv, wo, hbf, wqb, wkb, wvb, woh,
                                        cost, sint);
  gemm_qkv_kernel<<<1536, 256, 0, stream>>>(hbf, wqb, qbf);
  transpose_v_kernel<<<2048, 256, 0, stream>>>(vbf, vT);
  rope_k_kernel<<<4096, 256, 0, stream>>>(kbf, pid, cost, sint);
  attn_mfma_kernel<<<512, 256, 0, stream>>>(qbf, kbf, vT, pid, cost, sint, aoh);
  gemm_out_kernel<<<512, 256, 0, stream>>>(aoh, woh, out);
}